// Round 16
// baseline (608.305 us; speedup 1.0000x reference)
//
#include <hip/hip_runtime.h>
#include <math.h>

#define IMG 768
#define TX 48
#define TY 24
#define KF 4
#define ITX (TX + 2 * KF)   // 56
#define ITY (TY + 2 * KF)   // 32
#define NBX (IMG / TX)      // 16
#define NBY (IMG / TY)      // 32 -> 512 blocks = exactly 2 per CU
#define NT 448              // 7 waves; staging = exactly 1 float4/thread
#define RES_SCALE 0.1f
#define NITER 64

typedef float v2f __attribute__((ext_vector_type(2)));

// erf LUT over t = |x| in [0, 5.8], 256 intervals, base-prime form:
// entry i = (E_i - i*dE_i, dE_i); r(aa) = fma(aa, slope, base').
// Linear-interp |err| <= 2.2e-5 (validated R13/R15: absmax 8192 vs thr 22609).
#define TAB_N 256
#define TAB_D (5.8f / 256.0f)
#define TAB_SCALE (256.0f / 5.8f)

__device__ __forceinline__ float erf_hp(float t) {
    float e = __builtin_amdgcn_exp2f(t * t * -0.72134752044448f);
    float kk = __builtin_amdgcn_rcpf(fmaf(0.23164188662f, t, 1.0f));
    float p = fmaf(1.061405429f, kk, -1.453152027f);
    p = fmaf(p, kk, 1.421413741f);
    p = fmaf(p, kk, -0.284496736f);
    p = fmaf(p, kk, 0.254829592f);
    p *= kk;
    return fmaf(-e, p, 1.0f);
}

// 2*gelu(x) via LUT: 7 VALU + 1 ds_read_b64, no trans.
__device__ __forceinline__ float gelu2_lut(float x, const float2* __restrict__ tab) {
    float aa = fminf(fabsf(x) * TAB_SCALE, 255.999f);
    float2 ts = tab[(int)aa];
    float r = fmaf(aa, ts.y, ts.x);
    return fmaf(fabsf(x), r, x);
}

__device__ __forceinline__ float bilinear8(const float* __restrict__ seed,
                                           int gy, int gx) {
    float sy = fmaf((float)gy, 0.0104166667f, -0.4947916667f);
    float sx = fmaf((float)gx, 0.0104166667f, -0.4947916667f);
    float fy = floorf(sy), fx = floorf(sx);
    float wy = sy - fy, wx = sx - fx;
    int y0 = (int)fy, x0 = (int)fx;
    int y0c = min(max(y0, 0), 7), y1c = min(max(y0 + 1, 0), 7);
    int x0c = min(max(x0, 0), 7), x1c = min(max(x0 + 1, 0), 7);
    float v00 = seed[y0c * 8 + x0c], v01 = seed[y0c * 8 + x1c];
    float v10 = seed[y1c * 8 + x0c], v11 = seed[y1c * 8 + x1c];
    float top = v00 + wx * (v01 - v00);
    float bot = v10 + wx * (v11 - v10);
    return top + wy * (bot - top);
}

// R15 structure + K-packed conv: h = sum_t w_t*n_t computed as 4 v_pk_fma_f32
// (reduction-dim pairs) + 1 scalar fma + horizontal add. Weight pairs are
// consecutive memory -> s_load_dwordx2 (even ch: taps (0,1)(2,3)(4,5)(6,7)+w8;
// odd ch: w0+(1,2)(3,4)(5,6)(7,8) -- both phases 8B-aligned). Tap pairs are
// same-base LDS dwords within 255-dword window -> single ds_read2_b32 each.
// No operand splats anywhere.
template <bool FIRST>
__global__ void __launch_bounds__(NT)
__attribute__((amdgpu_waves_per_eu(2, 4)))
fused_steps(
        const float* __restrict__ seed,
        const float* __restrict__ xin, float* __restrict__ xout,
        const float* __restrict__ gw1, const float* __restrict__ gb1,
        const float* __restrict__ gw2, const float* __restrict__ gb2) {
    __shared__ float buf[2][ITY * ITX];   // 14336 B
    __shared__ float2 gtab[TAB_N];        // +2048 B
    const int tid = threadIdx.x;
    const int bx = blockIdx.x % NBX, by = blockIdx.x / NBX;
    const int gx0 = bx * TX - KF, gy0 = by * TY - KF;
    const bool border = (bx == 0) | (bx == NBX - 1) | (by == 0) | (by == NBY - 1);

    if (tid < TAB_N) {
        float t0 = tid * TAB_D;
        float e0 = erf_hp(t0);
        float de = erf_hp(t0 + TAB_D) - e0;
        gtab[tid] = make_float2(fmaf(-de, (float)tid, e0), de);
    }

    // ---- stage 56x32 input tile (zeros outside image = 'SAME' zero pad) ----
    if (FIRST) {
        for (int t = tid; t < ITY * ITX; t += NT) {
            int r = t / ITX, c = t - r * ITX;
            int gy = gy0 + r, gx = gx0 + c;
            float v = 0.0f;
            if (gy >= 0 && gy < IMG && gx >= 0 && gx < IMG)
                v = bilinear8(seed, gy, gx);
            buf[0][t] = v;
        }
    } else if (!border) {
        int r = tid / (ITX / 4), c4 = tid - r * (ITX / 4);
        *reinterpret_cast<float4*>(&buf[0][r * ITX + c4 * 4]) =
            *reinterpret_cast<const float4*>(&xin[(gy0 + r) * IMG + gx0 + c4 * 4]);
    } else {
        for (int t = tid; t < ITY * ITX; t += NT) {
            int r = t / ITX, c = t - r * ITX;
            int gy = gy0 + r, gx = gx0 + c;
            float v = 0.0f;
            if (gy >= 0 && gy < IMG && gx >= 0 && gx < IMG) v = xin[gy * IMG + gx];
            buf[0][t] = v;
        }
    }
    __syncthreads();

    const float y0init = 2.0f * gb2[0];   // y accumulates 2*w2*gelu; v=fma(.05,y,n4)

    // hoist biases into pinned VGPRs (1-SGPR rule: fma(s_w, v_n, v_bias))
    float vb[16];
#pragma unroll
    for (int ch = 0; ch < 16; ++ch) vb[ch] = gb1[ch];
    asm volatile("" : "+v"(vb[0]), "+v"(vb[1]), "+v"(vb[2]), "+v"(vb[3]),
                      "+v"(vb[4]), "+v"(vb[5]), "+v"(vb[6]), "+v"(vb[7]),
                      "+v"(vb[8]), "+v"(vb[9]), "+v"(vb[10]), "+v"(vb[11]),
                      "+v"(vb[12]), "+v"(vb[13]), "+v"(vb[14]), "+v"(vb[15]));

#pragma unroll
    for (int j = 0; j < KF; ++j) {
        const int SX = ITX - 2 - 2 * j;    // 54,52,50,48
        const int SY = ITY - 2 - 2 * j;    // 30,28,26,24
        const int off = j + 1;
        const int total = SX * SY;
        const int B = (total + NT - 1) / NT;  // 4,4,3,3 (compile-time)
        const float* __restrict__ src = &buf[j & 1][0];
        float* __restrict__ dst = &buf[(j & 1) ^ 1][0];

        int rr[4], cc[4];
        bool ok[4];
        // tap pairs per pixel: even-set e0..e3 + n8; odd-set o0..o3 + n0
        v2f e0_[4], e1_[4], e2_[4], e3_[4], o0_[4], o1_[4], o2_[4], o3_[4];
        float n0s[4], n8s[4];
#pragma unroll
        for (int k = 0; k < B; ++k) {
            int p = tid + k * NT;
            ok[k] = p < total;
            if (!ok[k]) p = total - 1;
            int q = p / SX;
            rr[k] = off + q;
            cc[k] = off + (p - q * SX);
            const float* s0 = &src[(rr[k] - 1) * ITX + (cc[k] - 1)];
            // taps: n0..n8 at s0 offsets {0,1,2, 56,57,58, 112,113,114}
            v2f t;
            t.x = s0[0];   t.y = s0[1];   e0_[k] = t;   // (n0,n1)
            t.x = s0[2];   t.y = s0[56];  e1_[k] = t;   // (n2,n3)
            t.x = s0[57];  t.y = s0[58];  e2_[k] = t;   // (n4,n5)
            t.x = s0[112]; t.y = s0[113]; e3_[k] = t;   // (n6,n7)
            t.x = s0[1];   t.y = s0[2];   o0_[k] = t;   // (n1,n2)
            t.x = s0[56];  t.y = s0[57];  o1_[k] = t;   // (n3,n4)
            t.x = s0[58];  t.y = s0[112]; o2_[k] = t;   // (n5,n6)
            t.x = s0[113]; t.y = s0[114]; o3_[k] = t;   // (n7,n8)
            n0s[k] = s0[0];
            n8s[k] = s0[114];
        }
        float y[4];
#pragma unroll
        for (int k = 0; k < B; ++k) y[k] = y0init;

#pragma unroll
        for (int cp = 0; cp < 8; ++cp) {
            // ---- even channel: pairs (0,1)(2,3)(4,5)(6,7) + scalar w8 ----
            {
                const int ch = 2 * cp;
                const float* wc = &gw1[ch * 9];                      // 8B-aligned
                v2f w01 = *reinterpret_cast<const v2f*>(wc + 0);
                v2f w23 = *reinterpret_cast<const v2f*>(wc + 2);
                v2f w45 = *reinterpret_cast<const v2f*>(wc + 4);
                v2f w67 = *reinterpret_cast<const v2f*>(wc + 6);
                const float w8 = wc[8];
                const float w2c = gw2[ch];
                float h[4];
#pragma unroll
                for (int k = 0; k < B; ++k) {
                    v2f a = w01 * e0_[k];
                    a = __builtin_elementwise_fma(w23, e1_[k], a);
                    a = __builtin_elementwise_fma(w45, e2_[k], a);
                    a = __builtin_elementwise_fma(w67, e3_[k], a);
                    h[k] = fmaf(w8, n8s[k], vb[ch]) + a.x + a.y;
                }
                if (B == 4) asm volatile("" : "+v"(h[0]), "+v"(h[1]), "+v"(h[2]), "+v"(h[3]));
                else        asm volatile("" : "+v"(h[0]), "+v"(h[1]), "+v"(h[2]));
#pragma unroll
                for (int k = 0; k < B; ++k)
                    y[k] = fmaf(w2c, gelu2_lut(h[k], gtab), y[k]);
            }
            // ---- odd channel: scalar w0 + pairs (1,2)(3,4)(5,6)(7,8) ----
            {
                const int ch = 2 * cp + 1;
                const float* wc = &gw1[ch * 9];
                const float w0 = wc[0];
                v2f w12 = *reinterpret_cast<const v2f*>(wc + 1);     // 8B-aligned
                v2f w34 = *reinterpret_cast<const v2f*>(wc + 3);
                v2f w56 = *reinterpret_cast<const v2f*>(wc + 5);
                v2f w78 = *reinterpret_cast<const v2f*>(wc + 7);
                const float w2c = gw2[ch];
                float h[4];
#pragma unroll
                for (int k = 0; k < B; ++k) {
                    v2f a = w12 * o0_[k];
                    a = __builtin_elementwise_fma(w34, o1_[k], a);
                    a = __builtin_elementwise_fma(w56, o2_[k], a);
                    a = __builtin_elementwise_fma(w78, o3_[k], a);
                    h[k] = fmaf(w0, n0s[k], vb[ch]) + a.x + a.y;
                }
                if (B == 4) asm volatile("" : "+v"(h[0]), "+v"(h[1]), "+v"(h[2]), "+v"(h[3]));
                else        asm volatile("" : "+v"(h[0]), "+v"(h[1]), "+v"(h[2]));
#pragma unroll
                for (int k = 0; k < B; ++k)
                    y[k] = fmaf(w2c, gelu2_lut(h[k], gtab), y[k]);
            }
        }

#pragma unroll
        for (int k = 0; k < B; ++k) {
            float n4 = e2_[k].x;                         // center tap
            float v = fmaf(0.05f, y[k], n4);             // 0.1*(b2 + 0.5*y)+n4
            if (border) {
                int gy = gy0 + rr[k], gx = gx0 + cc[k];
                bool inimg = (gy >= 0) & (gy < IMG) & (gx >= 0) & (gx < IMG);
                if (!inimg) v = 0.0f;                    // zero padding stays 0
            }
            if (ok[k]) dst[rr[k] * ITX + cc[k]] = v;
        }
        __syncthreads();
    }

    // ---- drain inner 48x24 (always fully in-image; KF even -> buf[0]) ----
    {
        int t = tid;
        if (t < (TX / 4) * TY) {
            int r = t / (TX / 4), c4 = t - r * (TX / 4);
            *reinterpret_cast<float4*>(&xout[(gy0 + KF + r) * IMG + gx0 + KF + c4 * 4]) =
                *reinterpret_cast<const float4*>(&buf[0][(KF + r) * ITX + KF + c4 * 4]);
        }
    }
}

extern "C" void kernel_launch(void* const* d_in, const int* in_sizes, int n_in,
                              void* d_out, int out_size, void* d_ws, size_t ws_size,
                              hipStream_t stream) {
    const float* seed = (const float*)d_in[0];
    const float* w1   = (const float*)d_in[1];
    const float* b1   = (const float*)d_in[2];
    const float* w2   = (const float*)d_in[3];
    const float* b2   = (const float*)d_in[4];

    float* out = (float*)d_out;
    float* ws  = (float*)d_ws;

    float* a = out;
    float* b = ws;
    fused_steps<true><<<NBX * NBY, NT, 0, stream>>>(seed, a, b, w1, b1, w2, b2);
    { float* t = a; a = b; b = t; }
    for (int it = KF; it < NITER; it += KF) {
        fused_steps<false><<<NBX * NBY, NT, 0, stream>>>(seed, a, b, w1, b1, w2, b2);
        float* t = a; a = b; b = t;
    }
}

// Round 17
// 399.498 us; speedup vs baseline: 1.5227x; 1.5227x over previous
//
#include <hip/hip_runtime.h>
#include <math.h>

#define IMG 768
#define TX 48
#define TY 24
#define KF 4
#define ITX (TX + 2 * KF)   // 56
#define ITY (TY + 2 * KF)   // 32
#define NBX (IMG / TX)      // 16
#define NBY (IMG / TY)      // 32 -> 512 blocks = exactly 2 per CU
#define NT 448              // 7 waves; staging = exactly 1 float4/thread
#define RES_SCALE 0.1f
#define NITER 64

// erf LUT over t = |x| in [0, 5.8], 256 intervals, base-prime form:
// entry i = (E_i - i*dE_i, dE_i) with E(t)=erf(t/sqrt2), so
// r(aa) = fma(aa, slope, base') for aa in [i,i+1) — no cvt-back/sub.
// Linear-interp |err| <= 2.2e-5 (validated R13/R15: absmax 8192 vs 22609).
// idx clamps at 255.999 -> r ~= 1 -> exact relu saturation for |x| > 5.8.
#define TAB_N 256
#define TAB_D (5.8f / 256.0f)
#define TAB_SCALE (256.0f / 5.8f)

// High-precision erf(t/sqrt2), t>=0 (A&S 7.1.26, |err|<1.5e-7) — used ONLY
// to build the table (2 evals/thread, once per launch).
__device__ __forceinline__ float erf_hp(float t) {
    float e = __builtin_amdgcn_exp2f(t * t * -0.72134752044448f);  // e^{-t^2/2}
    float kk = __builtin_amdgcn_rcpf(fmaf(0.23164188662f, t, 1.0f));
    float p = fmaf(1.061405429f, kk, -1.453152027f);
    p = fmaf(p, kk, 1.421413741f);
    p = fmaf(p, kk, -0.284496736f);
    p = fmaf(p, kk, 0.254829592f);
    p *= kk;
    return fmaf(-e, p, 1.0f);
}

// 2*gelu(x) via LUT: 7 VALU + 1 ds_read_b64, no trans, no cvt-back.
__device__ __forceinline__ float gelu2_lut(float x, const float2* __restrict__ tab) {
    float aa = fminf(fabsf(x) * TAB_SCALE, 255.999f);
    float2 ts = tab[(int)aa];           // ds_read_b64 (base', slope)
    float r = fmaf(aa, ts.y, ts.x);     // erf(|x|/sqrt2) in [0,1]
    return fmaf(fabsf(x), r, x);        // abs is a free VOP3 modifier
}

// F.interpolate(bilinear, align_corners=False) from the 8x8 seed,
// half-pixel centers; edge handling == index clamp.
__device__ __forceinline__ float bilinear8(const float* __restrict__ seed,
                                           int gy, int gx) {
    float sy = fmaf((float)gy, 0.0104166667f, -0.4947916667f);  // (gy+.5)/96-.5
    float sx = fmaf((float)gx, 0.0104166667f, -0.4947916667f);
    float fy = floorf(sy), fx = floorf(sx);
    float wy = sy - fy, wx = sx - fx;
    int y0 = (int)fy, x0 = (int)fx;
    int y0c = min(max(y0, 0), 7), y1c = min(max(y0 + 1, 0), 7);
    int x0c = min(max(x0, 0), 7), x1c = min(max(x0 + 1, 0), 7);
    float v00 = seed[y0c * 8 + x0c], v01 = seed[y0c * 8 + x1c];
    float v10 = seed[y1c * 8 + x0c], v11 = seed[y1c * 8 + x1c];
    float top = v00 + wx * (v01 - v00);
    float bot = v10 + wx * (v11 - v10);
    return top + wy * (bot - top);
}

// R15 structure (proven best: 48x24 tile, KF=4 shrinking halo, 2 blocks/CU,
// taps-outer/channel-accumulator scalar conv, bias + half-w2 hoisted to
// pinned VGPRs, LDS erf LUT). NEW: the LAST step (j=3) writes its results
// DIRECTLY to global — its valid region is exactly the block's 48x24 output
// tile (always fully in-image) — eliminating 1152 LDS writes, one barrier,
// and the entire drain loop per block.
template <bool FIRST>
__global__ void __launch_bounds__(NT)
__attribute__((amdgpu_waves_per_eu(2, 4)))
fused_steps(
        const float* __restrict__ seed,
        const float* __restrict__ xin, float* __restrict__ xout,
        const float* __restrict__ gw1, const float* __restrict__ gb1,
        const float* __restrict__ gw2, const float* __restrict__ gb2) {
    __shared__ float buf[2][ITY * ITX];   // 2 x 32x56 x 4B = 14336 B
    __shared__ float2 gtab[TAB_N];        // +2048 B = 16384 B total
    const int tid = threadIdx.x;
    const int bx = blockIdx.x % NBX, by = blockIdx.x / NBX;
    const int gx0 = bx * TX - KF, gy0 = by * TY - KF;
    const bool border = (bx == 0) | (bx == NBX - 1) | (by == 0) | (by == NBY - 1);

    // ---- build erf table (once per block; ordered by the staging barrier) ----
    if (tid < TAB_N) {
        float t0 = tid * TAB_D;
        float e0 = erf_hp(t0);
        float de = erf_hp(t0 + TAB_D) - e0;
        gtab[tid] = make_float2(fmaf(-de, (float)tid, e0), de);  // (base', slope)
    }

    // ---- stage 56x32 input tile (zeros outside image = 'SAME' zero pad) ----
    if (FIRST) {
        for (int t = tid; t < ITY * ITX; t += NT) {
            int r = t / ITX, c = t - r * ITX;
            int gy = gy0 + r, gx = gx0 + c;
            float v = 0.0f;
            if (gy >= 0 && gy < IMG && gx >= 0 && gx < IMG)
                v = bilinear8(seed, gy, gx);
            buf[0][t] = v;
        }
    } else if (!border) {
        // exactly one float4 per thread: 14*32 = 448
        int r = tid / (ITX / 4), c4 = tid - r * (ITX / 4);
        *reinterpret_cast<float4*>(&buf[0][r * ITX + c4 * 4]) =
            *reinterpret_cast<const float4*>(&xin[(gy0 + r) * IMG + gx0 + c4 * 4]);
    } else {
        for (int t = tid; t < ITY * ITX; t += NT) {   // 4 iters exact
            int r = t / ITX, c = t - r * ITX;
            int gy = gy0 + r, gx = gx0 + c;
            float v = 0.0f;
            if (gy >= 0 && gy < IMG && gx >= 0 && gx < IMG) v = xin[gy * IMG + gx];
            buf[0][t] = v;
        }
    }
    __syncthreads();

    const float b2v = gb2[0];

    // hoist biases AND half-w2 into pinned VGPRs once (kills 16 per-px
    // s->v movs and 16 per-px 0.5*h muls respectively)
    float vb[16], w2h[16];
#pragma unroll
    for (int ch = 0; ch < 16; ++ch) { vb[ch] = gb1[ch]; w2h[ch] = gw2[ch] * 0.5f; }
    asm volatile("" : "+v"(vb[0]), "+v"(vb[1]), "+v"(vb[2]), "+v"(vb[3]),
                      "+v"(vb[4]), "+v"(vb[5]), "+v"(vb[6]), "+v"(vb[7]),
                      "+v"(vb[8]), "+v"(vb[9]), "+v"(vb[10]), "+v"(vb[11]),
                      "+v"(vb[12]), "+v"(vb[13]), "+v"(vb[14]), "+v"(vb[15]));
    asm volatile("" : "+v"(w2h[0]), "+v"(w2h[1]), "+v"(w2h[2]), "+v"(w2h[3]),
                      "+v"(w2h[4]), "+v"(w2h[5]), "+v"(w2h[6]), "+v"(w2h[7]),
                      "+v"(w2h[8]), "+v"(w2h[9]), "+v"(w2h[10]), "+v"(w2h[11]),
                      "+v"(w2h[12]), "+v"(w2h[13]), "+v"(w2h[14]), "+v"(w2h[15]));

#pragma unroll
    for (int j = 0; j < KF; ++j) {
        const int SX = ITX - 2 - 2 * j;    // 54,52,50,48
        const int SY = ITY - 2 - 2 * j;    // 30,28,26,24
        const int off = j + 1;
        const int total = SX * SY;         // 1620,1456,1300,1152
        const int B = (total + NT - 1) / NT;  // 4,4,3,3 (compile-time)
        const bool LAST = (j == KF - 1);   // last step: 48x24 == output tile
        const float* __restrict__ src = &buf[j & 1][0];
        float* __restrict__ dst = &buf[(j & 1) ^ 1][0];

#pragma unroll
        for (int k = 0; k < B; ++k) {
            int p = tid + k * NT;
            bool ok = p < total;
            if (!ok) p = total - 1;        // clamp: duplicate of a valid pixel
            int q = p / SX;                // SX compile-time -> magic mul
            int r = off + q, c = off + (p - q * SX);
            const float* s0 = &src[(r - 1) * ITX + (c - 1)];
            float n0 = s0[0],           n1 = s0[1],           n2 = s0[2];
            float n3 = s0[ITX],         n4 = s0[ITX + 1],     n5 = s0[ITX + 2];
            float n6 = s0[2 * ITX],     n7 = s0[2 * ITX + 1], n8 = s0[2 * ITX + 2];

            // phase 1: 16 independent conv chains (ILP=16)
            float h[16];
#pragma unroll
            for (int ch = 0; ch < 16; ++ch) {
                const float* wc = &gw1[ch * 9];   // uniform -> s_load
                float t = fmaf(wc[0], n0, vb[ch]);
                t = fmaf(wc[1], n1, t);
                t = fmaf(wc[2], n2, t);
                t = fmaf(wc[3], n3, t);
                t = fmaf(wc[4], n4, t);
                t = fmaf(wc[5], n5, t);
                t = fmaf(wc[6], n6, t);
                t = fmaf(wc[7], n7, t);
                t = fmaf(wc[8], n8, t);
                h[ch] = t;
            }
            // zero-cost fence: pin the two-phase schedule (ILP=16 conv, then
            // activations) — prevents the R6 serializing loop interchange
            asm volatile("" : "+v"(h[0]), "+v"(h[1]), "+v"(h[2]), "+v"(h[3]),
                              "+v"(h[4]), "+v"(h[5]), "+v"(h[6]), "+v"(h[7]),
                              "+v"(h[8]), "+v"(h[9]), "+v"(h[10]), "+v"(h[11]),
                              "+v"(h[12]), "+v"(h[13]), "+v"(h[14]), "+v"(h[15]));

            // phase 2: 16 independent LUT-GELU + accumulate.
            // y += (0.5*w2) * (h + |h|*erf(|h|/sqrt2))  == w2 * gelu(h)
            float y = b2v;
#pragma unroll
            for (int ch = 0; ch < 16; ++ch)
                y = fmaf(w2h[ch], gelu2_lut(h[ch], gtab), y);

            float v = fmaf(RES_SCALE, y, n4);
            if (LAST) {
                // j=3 region (48x24 @ off=4) IS the output tile: always fully
                // in-image -> no border mask; write global directly (no LDS
                // write, no final barrier, no drain pass).
                if (ok) xout[(gy0 + r) * IMG + (gx0 + c)] = v;
            } else {
                if (border) {
                    int gy = gy0 + r, gx = gx0 + c;
                    bool inimg = (gy >= 0) & (gy < IMG) & (gx >= 0) & (gx < IMG);
                    // ghost pixels outside image stay 0 every iteration
                    if (!inimg) v = 0.0f;
                }
                if (ok) dst[r * ITX + c] = v;
            }
        }
        if (!LAST) __syncthreads();
    }
}

extern "C" void kernel_launch(void* const* d_in, const int* in_sizes, int n_in,
                              void* d_out, int out_size, void* d_ws, size_t ws_size,
                              hipStream_t stream) {
    const float* seed = (const float*)d_in[0];
    const float* w1   = (const float*)d_in[1];
    const float* b1   = (const float*)d_in[2];
    const float* w2   = (const float*)d_in[3];
    const float* b2   = (const float*)d_in[4];
    // d_in[5]/d_in[6] are rows/cols = 768/768 (fixed by setup_inputs)

    float* out = (float*)d_out;
    float* ws  = (float*)d_ws;   // second ping-pong buffer (2.36 MB)

    float* a = out;
    float* b = ws;
    // 16 launches; first fuses the bilinear resize; even count -> ends in d_out
    fused_steps<true><<<NBX * NBY, NT, 0, stream>>>(seed, a, b, w1, b1, w2, b2);
    { float* t = a; a = b; b = t; }
    for (int it = KF; it < NITER; it += KF) {
        fused_steps<false><<<NBX * NBY, NT, 0, stream>>>(seed, a, b, w1, b1, w2, b2);
        float* t = a; a = b; b = t;
    }
}

// Round 18
// 385.917 us; speedup vs baseline: 1.5763x; 1.0352x over previous
//
#include <hip/hip_runtime.h>
#include <math.h>

#define IMG 768
#define TX 48
#define TY 24
#define KF 4
#define ITX (TX + 2 * KF)   // 56
#define ITY (TY + 2 * KF)   // 32
#define NBX (IMG / TX)      // 16
#define NBY (IMG / TY)      // 32 -> 512 blocks = exactly 2 per CU
#define NT 448              // 7 waves; staging = exactly 1 float4/thread
#define RES_SCALE 0.1f
#define NITER 64

// erf LUT over t = |x| in [0, 5.8], 256 intervals, base-prime form:
// entry i = (E_i - i*dE_i, dE_i) with E(t)=erf(t/sqrt2), so
// r(aa) = fma(aa, slope, base') for aa in [i,i+1) — no cvt-back/sub.
// Linear-interp |err| <= 2.2e-5 (validated R13/R15/R17: absmax 8192 vs 22609).
// idx clamps at 255.999 -> r ~= 1 -> exact relu saturation for |x| > 5.8.
#define TAB_N 256
#define TAB_D (5.8f / 256.0f)
#define TAB_SCALE (256.0f / 5.8f)

// High-precision erf(t/sqrt2), t>=0 (A&S 7.1.26, |err|<1.5e-7) — used ONLY
// to build the table (2 evals/thread, once per launch).
__device__ __forceinline__ float erf_hp(float t) {
    float e = __builtin_amdgcn_exp2f(t * t * -0.72134752044448f);  // e^{-t^2/2}
    float kk = __builtin_amdgcn_rcpf(fmaf(0.23164188662f, t, 1.0f));
    float p = fmaf(1.061405429f, kk, -1.453152027f);
    p = fmaf(p, kk, 1.421413741f);
    p = fmaf(p, kk, -0.284496736f);
    p = fmaf(p, kk, 0.254829592f);
    p *= kk;
    return fmaf(-e, p, 1.0f);
}

// 2*gelu(x) via LUT: 6 VALU + 1 ds_read_b64, no trans, no cvt-back.
__device__ __forceinline__ float gelu2_lut(float x, const float2* __restrict__ tab) {
    float aa = fminf(fabsf(x) * TAB_SCALE, 255.999f);
    float2 ts = tab[(int)aa];           // ds_read_b64 (base', slope)
    float r = fmaf(aa, ts.y, ts.x);     // erf(|x|/sqrt2) in [0,1]
    return fmaf(fabsf(x), r, x);        // abs is a free VOP3 modifier
}

// F.interpolate(bilinear, align_corners=False) from the 8x8 seed,
// half-pixel centers; edge handling == index clamp.
__device__ __forceinline__ float bilinear8(const float* __restrict__ seed,
                                           int gy, int gx) {
    float sy = fmaf((float)gy, 0.0104166667f, -0.4947916667f);  // (gy+.5)/96-.5
    float sx = fmaf((float)gx, 0.0104166667f, -0.4947916667f);
    float fy = floorf(sy), fx = floorf(sx);
    float wy = sy - fy, wx = sx - fx;
    int y0 = (int)fy, x0 = (int)fx;
    int y0c = min(max(y0, 0), 7), y1c = min(max(y0 + 1, 0), 7);
    int x0c = min(max(x0, 0), 7), x1c = min(max(x0 + 1, 0), 7);
    float v00 = seed[y0c * 8 + x0c], v01 = seed[y0c * 8 + x1c];
    float v10 = seed[y1c * 8 + x0c], v11 = seed[y1c * 8 + x1c];
    float top = v00 + wx * (v01 - v00);
    float bot = v10 + wx * (v11 - v10);
    return top + wy * (bot - top);
}

// R17 structure (48x24 tile, KF=4 shrinking halo, 2 blocks/CU, taps-outer/
// channel-accumulator conv, bias + half-w2 hoisted, LDS erf LUT, last step
// writes global directly). NEW: guarded k-loop instead of clamp-duplicate —
// out-of-range WAVES skip the whole body via s_cbranch_execz (tid-contiguous
// mapping => inactive lanes contiguous => whole waves exec=0). Issued
// px-slots 6272 -> 5632 per block-dispatch (-10.2%); k=0..2 guards fold away
// at compile time (provably in-range).
template <bool FIRST>
__global__ void __launch_bounds__(NT)
__attribute__((amdgpu_waves_per_eu(2, 4)))
fused_steps(
        const float* __restrict__ seed,
        const float* __restrict__ xin, float* __restrict__ xout,
        const float* __restrict__ gw1, const float* __restrict__ gb1,
        const float* __restrict__ gw2, const float* __restrict__ gb2) {
    __shared__ float buf[2][ITY * ITX];   // 2 x 32x56 x 4B = 14336 B
    __shared__ float2 gtab[TAB_N];        // +2048 B = 16384 B total
    const int tid = threadIdx.x;
    const int bx = blockIdx.x % NBX, by = blockIdx.x / NBX;
    const int gx0 = bx * TX - KF, gy0 = by * TY - KF;
    const bool border = (bx == 0) | (bx == NBX - 1) | (by == 0) | (by == NBY - 1);

    // ---- build erf table (once per block; ordered by the staging barrier) ----
    if (tid < TAB_N) {
        float t0 = tid * TAB_D;
        float e0 = erf_hp(t0);
        float de = erf_hp(t0 + TAB_D) - e0;
        gtab[tid] = make_float2(fmaf(-de, (float)tid, e0), de);  // (base', slope)
    }

    // ---- stage 56x32 input tile (zeros outside image = 'SAME' zero pad) ----
    if (FIRST) {
        for (int t = tid; t < ITY * ITX; t += NT) {
            int r = t / ITX, c = t - r * ITX;
            int gy = gy0 + r, gx = gx0 + c;
            float v = 0.0f;
            if (gy >= 0 && gy < IMG && gx >= 0 && gx < IMG)
                v = bilinear8(seed, gy, gx);
            buf[0][t] = v;
        }
    } else if (!border) {
        // exactly one float4 per thread: 14*32 = 448
        int r = tid / (ITX / 4), c4 = tid - r * (ITX / 4);
        *reinterpret_cast<float4*>(&buf[0][r * ITX + c4 * 4]) =
            *reinterpret_cast<const float4*>(&xin[(gy0 + r) * IMG + gx0 + c4 * 4]);
    } else {
        for (int t = tid; t < ITY * ITX; t += NT) {   // 4 iters exact
            int r = t / ITX, c = t - r * ITX;
            int gy = gy0 + r, gx = gx0 + c;
            float v = 0.0f;
            if (gy >= 0 && gy < IMG && gx >= 0 && gx < IMG) v = xin[gy * IMG + gx];
            buf[0][t] = v;
        }
    }
    __syncthreads();

    const float b2v = gb2[0];

    // hoist biases AND half-w2 into pinned VGPRs once (kills 16 per-px
    // s->v movs and 16 per-px 0.5*h muls respectively)
    float vb[16], w2h[16];
#pragma unroll
    for (int ch = 0; ch < 16; ++ch) { vb[ch] = gb1[ch]; w2h[ch] = gw2[ch] * 0.5f; }
    asm volatile("" : "+v"(vb[0]), "+v"(vb[1]), "+v"(vb[2]), "+v"(vb[3]),
                      "+v"(vb[4]), "+v"(vb[5]), "+v"(vb[6]), "+v"(vb[7]),
                      "+v"(vb[8]), "+v"(vb[9]), "+v"(vb[10]), "+v"(vb[11]),
                      "+v"(vb[12]), "+v"(vb[13]), "+v"(vb[14]), "+v"(vb[15]));
    asm volatile("" : "+v"(w2h[0]), "+v"(w2h[1]), "+v"(w2h[2]), "+v"(w2h[3]),
                      "+v"(w2h[4]), "+v"(w2h[5]), "+v"(w2h[6]), "+v"(w2h[7]),
                      "+v"(w2h[8]), "+v"(w2h[9]), "+v"(w2h[10]), "+v"(w2h[11]),
                      "+v"(w2h[12]), "+v"(w2h[13]), "+v"(w2h[14]), "+v"(w2h[15]));

#pragma unroll
    for (int j = 0; j < KF; ++j) {
        const int SX = ITX - 2 - 2 * j;    // 54,52,50,48
        const int SY = ITY - 2 - 2 * j;    // 30,28,26,24
        const int off = j + 1;
        const int total = SX * SY;         // 1620,1456,1300,1152
        const int B = (total + NT - 1) / NT;  // 4,4,3,3 (compile-time)
        const bool LAST = (j == KF - 1);   // last step: 48x24 == output tile
        const float* __restrict__ src = &buf[j & 1][0];
        float* __restrict__ dst = &buf[(j & 1) ^ 1][0];

#pragma unroll
        for (int k = 0; k < B; ++k) {
            int p = tid + k * NT;
            if (p < total) {               // whole out-of-range waves execz-skip;
                                           // k<=2 guards fold away (provable)
                int q = p / SX;            // SX compile-time -> magic mul
                int r = off + q, c = off + (p - q * SX);
                const float* s0 = &src[(r - 1) * ITX + (c - 1)];
                float n0 = s0[0],           n1 = s0[1],           n2 = s0[2];
                float n3 = s0[ITX],         n4 = s0[ITX + 1],     n5 = s0[ITX + 2];
                float n6 = s0[2 * ITX],     n7 = s0[2 * ITX + 1], n8 = s0[2 * ITX + 2];

                // phase 1: 16 independent conv chains (ILP=16)
                float h[16];
#pragma unroll
                for (int ch = 0; ch < 16; ++ch) {
                    const float* wc = &gw1[ch * 9];   // uniform -> s_load
                    float t = fmaf(wc[0], n0, vb[ch]);
                    t = fmaf(wc[1], n1, t);
                    t = fmaf(wc[2], n2, t);
                    t = fmaf(wc[3], n3, t);
                    t = fmaf(wc[4], n4, t);
                    t = fmaf(wc[5], n5, t);
                    t = fmaf(wc[6], n6, t);
                    t = fmaf(wc[7], n7, t);
                    t = fmaf(wc[8], n8, t);
                    h[ch] = t;
                }
                // zero-cost fence: pin the two-phase schedule (ILP=16 conv,
                // then activations) — prevents the R6 serializing interchange
                asm volatile("" : "+v"(h[0]), "+v"(h[1]), "+v"(h[2]), "+v"(h[3]),
                                  "+v"(h[4]), "+v"(h[5]), "+v"(h[6]), "+v"(h[7]),
                                  "+v"(h[8]), "+v"(h[9]), "+v"(h[10]), "+v"(h[11]),
                                  "+v"(h[12]), "+v"(h[13]), "+v"(h[14]), "+v"(h[15]));

                // phase 2: 16 independent LUT-GELU + accumulate.
                // y += (0.5*w2) * (h + |h|*erf(|h|/sqrt2))  == w2 * gelu(h)
                float y = b2v;
#pragma unroll
                for (int ch = 0; ch < 16; ++ch)
                    y = fmaf(w2h[ch], gelu2_lut(h[ch], gtab), y);

                float v = fmaf(RES_SCALE, y, n4);
                if (LAST) {
                    // j=3 region (48x24 @ off=4) IS the output tile: always
                    // fully in-image -> write global directly (no LDS write,
                    // no final barrier, no drain pass).
                    xout[(gy0 + r) * IMG + (gx0 + c)] = v;
                } else {
                    if (border) {
                        int gy = gy0 + r, gx = gx0 + c;
                        bool inimg = (gy >= 0) & (gy < IMG) & (gx >= 0) & (gx < IMG);
                        // ghost pixels outside image stay 0 every iteration
                        if (!inimg) v = 0.0f;
                    }
                    dst[r * ITX + c] = v;
                }
            }
        }
        if (!LAST) __syncthreads();
    }
}

extern "C" void kernel_launch(void* const* d_in, const int* in_sizes, int n_in,
                              void* d_out, int out_size, void* d_ws, size_t ws_size,
                              hipStream_t stream) {
    const float* seed = (const float*)d_in[0];
    const float* w1   = (const float*)d_in[1];
    const float* b1   = (const float*)d_in[2];
    const float* w2   = (const float*)d_in[3];
    const float* b2   = (const float*)d_in[4];
    // d_in[5]/d_in[6] are rows/cols = 768/768 (fixed by setup_inputs)

    float* out = (float*)d_out;
    float* ws  = (float*)d_ws;   // second ping-pong buffer (2.36 MB)

    float* a = out;
    float* b = ws;
    // 16 launches; first fuses the bilinear resize; even count -> ends in d_out
    fused_steps<true><<<NBX * NBY, NT, 0, stream>>>(seed, a, b, w1, b1, w2, b2);
    { float* t = a; a = b; b = t; }
    for (int it = KF; it < NITER; it += KF) {
        fused_steps<false><<<NBX * NBY, NT, 0, stream>>>(seed, a, b, w1, b1, w2, b2);
        float* t = a; a = b; b = t;
    }
}